// Round 7
// baseline (63.637 us; speedup 1.0000x reference)
//
#include <hip/hip_runtime.h>

// 1-D hash-grid embedder, 8 levels, 2 feats, fp32, B = 4.19M.
//
// Round-6 post-mortem: 2->4 blocks/CU was perfectly neutral (57.3->57.5us) ->
// the wall is a saturated pipe, not latency. Suspects: (a) the nt store flag
// (fills sustain 6.9 TB/s WITHOUT nt; nt was never isolated), (b) 4 conflicted
// ds_read_b64/iter overlapping poorly with the store drain.
//
// This version: (1) plain stores (NT removed); (2) packed {t,Delta} float4
// image so each level is ONE aligned ds_read_b128, lerp = t + w*Delta
// (staging computes Delta = t[e+1]-t[e]; deviation vs reference ~1e-11,
// threshold 2e-6). 65KB LDS -> 2 blocks/CU (proven free in round 6).
//
// Numerics: res = 16<<l power of two, fx = x*res exact,
// w = fx - floor(fx) bit-identical to reference (x - idx*gs)/gs.

#define NGP_BATCH   4194304
#define NGP_TSIZE   (1 << 19)
#define BLOCK       512
#define PPB         8192                // points per block
#define KITER       (PPB / (BLOCK/4))   // 64 iterations of 128 points

typedef float f32x4 __attribute__((ext_vector_type(4)));

__global__ __launch_bounds__(BLOCK) void hashenc_kernel(
    const float* __restrict__ x,
    const float* __restrict__ tables,
    float* __restrict__ out)
{
    // level l at off(l) = 16*((1<<l)-1), size 16<<l float4: {t.x, t.y, dx, dy}
    __shared__ float4 sm4[4080];   // 65280 B -> 2 blocks/CU

    const int tid = threadIdx.x;

    // ---- stage packed value+delta: sm4[off+e] = {t[e].x, t[e].y, t[e+1]-t[e]}
#pragma unroll
    for (int l = 0; l < 8; ++l) {
        const int n   = 16 << l;                 // e = idx in 0..res-1 (x < 1)
        const int off = 16 * ((1 << l) - 1);
        const float2* __restrict__ src =
            reinterpret_cast<const float2*>(tables) + (size_t)l * NGP_TSIZE;
        for (int e = tid; e < n; e += BLOCK) {
            const float2 a = src[e];
            const float2 b = src[e + 1];
            sm4[off + e] = make_float4(a.x, a.y, b.x - a.x, b.y - a.y);
        }
    }
    __syncthreads();

    const int q  = tid >> 2;
    const int s  = tid & 3;
    const int l0 = 2 * s;
    const int l1 = 2 * s + 1;
    const float res0 = (float)(16 << l0);
    const float res1 = (float)(16 << l1);
    const int   off0 = 16 * ((1 << l0) - 1);
    const int   off1 = 16 * ((1 << l1) - 1);

    const int P0 = blockIdx.x * PPB;
    f32x4* __restrict__ out4 = reinterpret_cast<f32x4*>(out);

#pragma unroll 4
    for (int k = 0; k < KITER; ++k) {
        const int   p  = P0 + q + 128 * k;
        const float xv = x[p];

        const float fx0 = xv * res0;             // exact pow2 scale
        const float fi0 = floorf(fx0);
        const float w0  = fx0 - fi0;             // == reference w
        const float4 e0 = sm4[off0 + (int)fi0];  // one ds_read_b128

        const float fx1 = xv * res1;
        const float fi1 = floorf(fx1);
        const float w1  = fx1 - fi1;
        const float4 e1 = sm4[off1 + (int)fi1];

        f32x4 r;
        r.x = e0.x + w0 * e0.z;                  // t + w*Delta (2 fma/level)
        r.y = e0.y + w0 * e0.w;
        r.z = e1.x + w1 * e1.z;
        r.w = e1.y + w1 * e1.w;

        out4[(size_t)p * 4 + s] = r;             // plain store, 1KB/wave burst
    }
}

extern "C" void kernel_launch(void* const* d_in, const int* in_sizes, int n_in,
                              void* d_out, int out_size, void* d_ws, size_t ws_size,
                              hipStream_t stream) {
    const float* x      = (const float*)d_in[0];
    const float* tables = (const float*)d_in[1];
    float*       out    = (float*)d_out;

    const int grid = NGP_BATCH / PPB;   // 512 blocks = 2 per CU resident
    hashenc_kernel<<<grid, BLOCK, 0, stream>>>(x, tables, out);
}

// Round 8
// 56.067 us; speedup vs baseline: 1.1350x; 1.1350x over previous
//
#include <hip/hip_runtime.h>

// 1-D hash-grid embedder, 8 levels, 2 feats, fp32, B = 4.19M.
//
// Ledger through round 7 (all refcheck'd, absmax 4.8e-7):
//   R1 global-gather 111us -> R3 4-thread/point + LDS + coalesced stores 66.3
//   -> R5 persistent 512 blocks + NT stores 57.3 -> R6 4 blocks/CU neutral
//   -> R7 NT removed = +6.3us REGRESSION (NT is a confirmed +6us win).
//   LDS instr mix (2xb128 vs 4xb64) and occupancy (16 vs 32 waves) both
//   isolated-neutral; wall at ~57us vs ~44us mixed-stream model.
// Untested structural lever: DISPATCH SLACK. Both 57us configs had
// blocks == residency cap exactly (zero slack -> straggler-CU tail on any
// uneven XCD assignment). This version: 33KB compact float2 image ->
// 4-resident/CU, 2048 blocks (PPB 2048) = ~8 block-lifetimes per CU so
// imbalance and staging amortize across generations. NT restored.
//
// Numerics: res = 16<<l power of two, fx = x*res exact,
// w = fx - floor(fx) bit-identical to reference (x - idx*gs)/gs.
// Lerp a + w*(b-a): ~1ulp-of-1e-4 from reference form, threshold 2e-6.

#define NGP_BATCH   4194304
#define NGP_TSIZE   (1 << 19)
#define BLOCK       512
#define PPB         2048                // points per block
#define KITER       (PPB / (BLOCK/4))   // 16 iterations of 128 points

typedef float f32x4 __attribute__((ext_vector_type(4)));

__global__ __launch_bounds__(BLOCK) void hashenc_kernel(
    const float* __restrict__ x,
    const float* __restrict__ tables,
    float* __restrict__ out)
{
    // level l at off(l) = 16*((1<<l)-1) + l, size (16<<l)+1 float2 entries
    __shared__ float2 sm[4088];   // 32704 B -> 4 blocks/CU resident

    const int tid = threadIdx.x;

    // ---- stage compact hot region: level l entries 0..(16<<l) ----
#pragma unroll
    for (int l = 0; l < 8; ++l) {
        const int n   = (16 << l) + 1;
        const int off = 16 * ((1 << l) - 1) + l;
        const float2* __restrict__ src =
            reinterpret_cast<const float2*>(tables) + (size_t)l * NGP_TSIZE;
        for (int e = tid; e < n; e += BLOCK)
            sm[off + e] = src[e];
    }
    __syncthreads();

    const int q  = tid >> 2;
    const int s  = tid & 3;
    const int l0 = 2 * s;
    const int l1 = 2 * s + 1;
    const float res0 = (float)(16 << l0);
    const float res1 = (float)(16 << l1);
    const int   off0 = 16 * ((1 << l0) - 1) + l0;
    const int   off1 = 16 * ((1 << l1) - 1) + l1;

    const int P0 = blockIdx.x * PPB;
    f32x4* __restrict__ out4 = reinterpret_cast<f32x4*>(out);

#pragma unroll 4
    for (int k = 0; k < KITER; ++k) {
        const int   p  = P0 + q + 128 * k;
        const float xv = x[p];

        const float fx0 = xv * res0;             // exact pow2 scale
        const float fi0 = floorf(fx0);
        const float w0  = fx0 - fi0;             // == reference w
        const int   i0  = off0 + (int)fi0;
        const float2 a0 = sm[i0];                // ds_read2_b64 pair
        const float2 b0 = sm[i0 + 1];

        const float fx1 = xv * res1;
        const float fi1 = floorf(fx1);
        const float w1  = fx1 - fi1;
        const int   i1  = off1 + (int)fi1;
        const float2 a1 = sm[i1];
        const float2 b1 = sm[i1 + 1];

        f32x4 r;
        r.x = fmaf(w0, b0.x - a0.x, a0.x);
        r.y = fmaf(w0, b0.y - a0.y, a0.y);
        r.z = fmaf(w1, b1.x - a1.x, a1.x);
        r.w = fmaf(w1, b1.y - a1.y, a1.y);

        __builtin_nontemporal_store(r, &out4[(size_t)p * 4 + s]);  // 1KB/wave
    }
}

extern "C" void kernel_launch(void* const* d_in, const int* in_sizes, int n_in,
                              void* d_out, int out_size, void* d_ws, size_t ws_size,
                              hipStream_t stream) {
    const float* x      = (const float*)d_in[0];
    const float* tables = (const float*)d_in[1];
    float*       out    = (float*)d_out;

    const int grid = NGP_BATCH / PPB;   // 2048 blocks = ~8 lifetimes per CU
    hashenc_kernel<<<grid, BLOCK, 0, stream>>>(x, tables, out);
}

// Round 9
// 54.197 us; speedup vs baseline: 1.1742x; 1.0345x over previous
//
#include <hip/hip_runtime.h>

// 1-D hash-grid embedder, 8 levels, 2 feats, fp32, B = 4.19M.
//
// Ledger (all refcheck'd, absmax 4.8e-7): R1 111us -> R3 66.3 (4-thr/point,
// LDS gather, coalesced 1KB wave stores) -> R5 57.3 (persistent + NT stores)
// -> R6 neutral (2x occupancy) -> R7 63.6 (NT removed: NT = +6us win)
// -> R8 56.1 (33KB compact image, dispatch slack +1us).
// Exonerated: occupancy, LDS instr mix/bank traffic, slack. Gap vs fill-rate
// floor (~40us) still ~16us.
//
// Round-9 theory: vmcnt retires IN ISSUE ORDER and counts stores too. With
// unroll-4, each body's x-loads sit after the previous body's 4 NT stores in
// program order, so waiting for x forces store-drain into the issue path at
// every body boundary. Fix: prefetch next body's x BEFORE this body's stores
// -> the load is older than any outstanding store; vmcnt(4) retires it
// without draining stores.
//
// Numerics: res = 16<<l power of two, fx = x*res exact, w = fx - floor(fx)
// bit-identical to reference. Lerp a + w*(b-a): ~1e-11 dev, threshold 2e-6.

#define NGP_BATCH   4194304
#define NGP_TSIZE   (1 << 19)
#define BLOCK       512
#define PPB         2048                // points per block
#define KITER       (PPB / (BLOCK/4))   // 16 iterations of 128 points
#define NBODY       (KITER / 4)         // 4 bodies of 4 iterations

typedef float f32x4 __attribute__((ext_vector_type(4)));

__global__ __launch_bounds__(BLOCK) void hashenc_kernel(
    const float* __restrict__ x,
    const float* __restrict__ tables,
    float* __restrict__ out)
{
    // level l at off(l) = 16*((1<<l)-1) + l, size (16<<l)+1 float2 entries
    __shared__ float2 sm[4088];   // 32704 B -> 4 blocks/CU resident

    const int tid = threadIdx.x;

    // ---- stage compact hot region: level l entries 0..(16<<l) ----
#pragma unroll
    for (int l = 0; l < 8; ++l) {
        const int n   = (16 << l) + 1;
        const int off = 16 * ((1 << l) - 1) + l;
        const float2* __restrict__ src =
            reinterpret_cast<const float2*>(tables) + (size_t)l * NGP_TSIZE;
        for (int e = tid; e < n; e += BLOCK)
            sm[off + e] = src[e];
    }
    __syncthreads();

    const int q  = tid >> 2;
    const int s  = tid & 3;
    const int l0 = 2 * s;
    const int l1 = 2 * s + 1;
    const float res0 = (float)(16 << l0);
    const float res1 = (float)(16 << l1);
    const int   off0 = 16 * ((1 << l0) - 1) + l0;
    const int   off1 = 16 * ((1 << l1) - 1) + l1;

    const int P0 = blockIdx.x * PPB;
    f32x4* __restrict__ out4 = reinterpret_cast<f32x4*>(out);

    float xc[4], xn[4];
#pragma unroll
    for (int j = 0; j < 4; ++j)
        xc[j] = x[P0 + q + 128 * j];

#pragma unroll
    for (int m = 0; m < NBODY; ++m) {
        // prefetch next body's x BEFORE any stores of this body (vmcnt order)
        if (m + 1 < NBODY) {
#pragma unroll
            for (int j = 0; j < 4; ++j)
                xn[j] = x[P0 + q + 128 * (4 * (m + 1) + j)];
        }

#pragma unroll
        for (int j = 0; j < 4; ++j) {
            const int   p  = P0 + q + 128 * (4 * m + j);
            const float xv = xc[j];

            const float fx0 = xv * res0;             // exact pow2 scale
            const float fi0 = floorf(fx0);
            const float w0  = fx0 - fi0;             // == reference w
            const int   i0  = off0 + (int)fi0;
            const float2 a0 = sm[i0];
            const float2 b0 = sm[i0 + 1];

            const float fx1 = xv * res1;
            const float fi1 = floorf(fx1);
            const float w1  = fx1 - fi1;
            const int   i1  = off1 + (int)fi1;
            const float2 a1 = sm[i1];
            const float2 b1 = sm[i1 + 1];

            f32x4 r;
            r.x = fmaf(w0, b0.x - a0.x, a0.x);
            r.y = fmaf(w0, b0.y - a0.y, a0.y);
            r.z = fmaf(w1, b1.x - a1.x, a1.x);
            r.w = fmaf(w1, b1.y - a1.y, a1.y);

            __builtin_nontemporal_store(r, &out4[(size_t)p * 4 + s]);
        }

        if (m + 1 < NBODY) {
#pragma unroll
            for (int j = 0; j < 4; ++j)
                xc[j] = xn[j];
        }
    }
}

extern "C" void kernel_launch(void* const* d_in, const int* in_sizes, int n_in,
                              void* d_out, int out_size, void* d_ws, size_t ws_size,
                              hipStream_t stream) {
    const float* x      = (const float*)d_in[0];
    const float* tables = (const float*)d_in[1];
    float*       out    = (float*)d_out;

    const int grid = NGP_BATCH / PPB;   // 2048 blocks
    hashenc_kernel<<<grid, BLOCK, 0, stream>>>(x, tables, out);
}

// Round 10
// 51.658 us; speedup vs baseline: 1.2319x; 1.0492x over previous
//
#include <hip/hip_runtime.h>

// 1-D hash-grid embedder, 8 levels, 2 feats, fp32, B = 4.19M.
//
// Ledger (all refcheck'd, absmax 4.8e-7): R1 111 -> R3 66.3 (4-thr/point, LDS,
// coalesced 1KB wave stores) -> R5 57.3 (persistent + NT) -> R7 63.6 (NT
// removed: NT=+6us) -> R8 56.1 (compact image + slack) -> R9 54.2 (x-prefetch
// before stores, vmcnt ordering +2us).
// Exonerated: occupancy (2x neutral), slack, b64-vs-b128 mix at EQUAL bank
// cycles. Remaining theory: LDS gather pipe is co-critical (~21-30us/CU of
// conflicted ds_read vs 44us store drain; imperfect overlap = the ~11us gap).
// This round HALVES LDS instructions: packed {t, Delta} float4 image -> ONE
// ds_read_b128 per level per point (R7's gather form, but now WITH NT -- the
// two wins were never combined). Lerp t + w*Delta, dev ~1e-11 vs 2e-6 thr.
//
// Numerics: res = 16<<l power of two, fx = x*res exact, w = fx - floor(fx)
// bit-identical to reference.

#define NGP_BATCH   4194304
#define NGP_TSIZE   (1 << 19)
#define BLOCK       512
#define PPB         4096                // points per block
#define KITER       (PPB / (BLOCK/4))   // 32 iterations of 128 points
#define NBODY       (KITER / 4)         // 8 bodies of 4 iterations

typedef float f32x4 __attribute__((ext_vector_type(4)));

__global__ __launch_bounds__(BLOCK) void hashenc_kernel(
    const float* __restrict__ x,
    const float* __restrict__ tables,
    float* __restrict__ out)
{
    // level l at off(l) = 16*((1<<l)-1), size 16<<l float4: {t.x, t.y, dx, dy}
    __shared__ float4 sm4[4080];   // 65280 B -> 2 blocks/CU resident

    const int tid = threadIdx.x;

    // ---- stage packed value+delta: sm4[off+e] = {t[e], t[e+1]-t[e]} ----
#pragma unroll
    for (int l = 0; l < 8; ++l) {
        const int n   = 16 << l;                 // e = idx in 0..res-1 (x < 1)
        const int off = 16 * ((1 << l) - 1);
        const float2* __restrict__ src =
            reinterpret_cast<const float2*>(tables) + (size_t)l * NGP_TSIZE;
        for (int e = tid; e < n; e += BLOCK) {
            const float2 a = src[e];
            const float2 b = src[e + 1];
            sm4[off + e] = make_float4(a.x, a.y, b.x - a.x, b.y - a.y);
        }
    }
    __syncthreads();

    const int q  = tid >> 2;
    const int s  = tid & 3;
    const int l0 = 2 * s;
    const int l1 = 2 * s + 1;
    const float res0 = (float)(16 << l0);
    const float res1 = (float)(16 << l1);
    const int   off0 = 16 * ((1 << l0) - 1);
    const int   off1 = 16 * ((1 << l1) - 1);

    const int P0 = blockIdx.x * PPB;
    f32x4* __restrict__ out4 = reinterpret_cast<f32x4*>(out);

    float xc[4], xn[4];
#pragma unroll
    for (int j = 0; j < 4; ++j)
        xc[j] = x[P0 + q + 128 * j];

#pragma unroll
    for (int m = 0; m < NBODY; ++m) {
        // prefetch next body's x BEFORE this body's stores (vmcnt issue order)
        if (m + 1 < NBODY) {
#pragma unroll
            for (int j = 0; j < 4; ++j)
                xn[j] = x[P0 + q + 128 * (4 * (m + 1) + j)];
        }

#pragma unroll
        for (int j = 0; j < 4; ++j) {
            const int   p  = P0 + q + 128 * (4 * m + j);
            const float xv = xc[j];

            const float fx0 = xv * res0;             // exact pow2 scale
            const float fi0 = floorf(fx0);
            const float w0  = fx0 - fi0;             // == reference w
            const float4 e0 = sm4[off0 + (int)fi0];  // one ds_read_b128

            const float fx1 = xv * res1;
            const float fi1 = floorf(fx1);
            const float w1  = fx1 - fi1;
            const float4 e1 = sm4[off1 + (int)fi1];

            f32x4 r;
            r.x = fmaf(w0, e0.z, e0.x);              // t + w*Delta
            r.y = fmaf(w0, e0.w, e0.y);
            r.z = fmaf(w1, e1.z, e1.x);
            r.w = fmaf(w1, e1.w, e1.y);

            __builtin_nontemporal_store(r, &out4[(size_t)p * 4 + s]);
        }

        if (m + 1 < NBODY) {
#pragma unroll
            for (int j = 0; j < 4; ++j)
                xc[j] = xn[j];
        }
    }
}

extern "C" void kernel_launch(void* const* d_in, const int* in_sizes, int n_in,
                              void* d_out, int out_size, void* d_ws, size_t ws_size,
                              hipStream_t stream) {
    const float* x      = (const float*)d_in[0];
    const float* tables = (const float*)d_in[1];
    float*       out    = (float*)d_out;

    const int grid = NGP_BATCH / PPB;   // 1024 blocks, 2 generations of 512
    hashenc_kernel<<<grid, BLOCK, 0, stream>>>(x, tables, out);
}